// Round 1
// 371.920 us; speedup vs baseline: 1.0349x; 1.0349x over previous
//
#include <hip/hip_runtime.h>
#include <hip/hip_bf16.h>
#include <math.h>

// Problem constants: B=4, T=2048, D=1024, H=16, DH=64
constexpr int Mdim = 8192;   // B*T
constexpr int Ndim = 1024;
constexpr int Kdim = 1024;
constexpr int Tseq = 2048;
constexpr int NH   = 16;

typedef __attribute__((ext_vector_type(8))) short short8;   // 8 bf16 = 4 VGPRs
typedef __attribute__((ext_vector_type(4))) float floatx4;  // MFMA C/D frag

__device__ __forceinline__ unsigned short f2b(float f) {   // RNE
  unsigned int x = __builtin_bit_cast(unsigned int, f);
  x += 0x7fffu + ((x >> 16) & 1u);
  return (unsigned short)(x >> 16);
}
__device__ __forceinline__ unsigned int pk2(float a, float b) {  // fast 2xbf16
  unsigned int ua = __builtin_bit_cast(unsigned int, a) + 0x8000u;
  unsigned int ub = __builtin_bit_cast(unsigned int, b) + 0x8000u;
  return (ua >> 16) | (ub & 0xffff0000u);
}
// async global->LDS, 16B per lane; LDS dest = uniform base + lane*16
__device__ __forceinline__ void gld16(const void* g, const void* l) {
  __builtin_amdgcn_global_load_lds(
      (const __attribute__((address_space(1))) unsigned int*)(unsigned long long)g,
      (__attribute__((address_space(3))) unsigned int*)(unsigned int)(unsigned long long)l,
      16, 0, 0);
}
// raw barrier (no vmcnt drain) with compiler-level memory fences so C++ LDS
// reads / gld16 issues cannot migrate across phases.
__device__ __forceinline__ void bar() {
  asm volatile("" ::: "memory");
  __builtin_amdgcn_s_barrier();
  asm volatile("" ::: "memory");
}

// ---------------------------------------------------------------- casts
__global__ __launch_bounds__(256) void cast_k(
    const float* __restrict__ q, const float* __restrict__ k,
    const float* __restrict__ v, const float* __restrict__ wq,
    const float* __restrict__ wk, const float* __restrict__ wv,
    const float* __restrict__ wo,
    unsigned short* d0, unsigned short* d1, unsigned short* d2,
    unsigned short* d3, unsigned short* d4, unsigned short* d5,
    unsigned short* d6) {
  int y = blockIdx.y;
  const float* s = y == 0 ? q : y == 1 ? k : y == 2 ? v
                 : y == 3 ? wq : y == 4 ? wk : y == 5 ? wv : wo;
  unsigned short* d = y == 0 ? d0 : y == 1 ? d1 : y == 2 ? d2
                    : y == 3 ? d3 : y == 4 ? d4 : y == 5 ? d5 : d6;
  size_t n = (y < 3) ? (size_t)Mdim * Kdim : (size_t)Ndim * Kdim;
  size_t i = ((size_t)blockIdx.x * 256 + threadIdx.x) * 8;
  if (i >= n) return;
  float4 a = *(const float4*)(s + i);
  float4 b = *(const float4*)(s + i + 4);
  uint4 w;
  w.x = (unsigned)f2b(a.x) | ((unsigned)f2b(a.y) << 16);
  w.y = (unsigned)f2b(a.z) | ((unsigned)f2b(a.w) << 16);
  w.z = (unsigned)f2b(b.x) | ((unsigned)f2b(b.y) << 16);
  w.w = (unsigned)f2b(b.z) | ((unsigned)f2b(b.w) << 16);
  *(uint4*)(d + i) = w;
}

// ---------------------------------------------------------------- QKV GEMM
// 256x256 tile, BK=64, 8 waves (2M x 4N), 512 threads — 8-phase schedule
// (T3+T4 counted vmcnt + T5 setprio on top of T2 XOR swizzle).
// LDS: [parity][half 128x64] for A and B = 128 KiB, staged via
// global_load_lds w/ pre-swizzled global source (linear LDS dest).
// Pipeline: prologue stages tiles 0,1; during tile t phases 3/4 stage tile
// t+2 into parity t&1 (B at ph3 — B reads of t closed at ph2 barrier;
// A at ph4 — A reads closed at ph3 barrier). Boundary: s_waitcnt vmcnt(8)
// (8 newest = tile t+2's loads), vmcnt(0) only entering the last tile.
// MFMA operands SWAPPED (A-op = W rows) -> C^T frag: 4 consecutive n per
// lane -> packed float4/ushort4 epilogue stores.
// z: 0 = Q -> Qh bf16 split-head; 1 = K -> Kout f32 + Kh bf16;
//    2 = V -> Vout f32 + VTg bf16 [B,H,64,T].
__launch_bounds__(512, 2)
__global__ void gemm_qkv(const unsigned short* __restrict__ Aq,
                         const unsigned short* __restrict__ Ak,
                         const unsigned short* __restrict__ Av,
                         const unsigned short* __restrict__ Wq,
                         const unsigned short* __restrict__ Wk,
                         const unsigned short* __restrict__ Wv,
                         unsigned short* __restrict__ Qh,
                         unsigned short* __restrict__ Kh,
                         float* __restrict__ Kout,
                         unsigned short* __restrict__ VTg,
                         float* __restrict__ Vout) {
  __shared__ __align__(16) unsigned short As[2][2][8192];  // [par][half][128*64]
  __shared__ __align__(16) unsigned short Bs[2][2][8192];

  const int z = blockIdx.z;
  const unsigned short* __restrict__ A = z == 0 ? Aq : z == 1 ? Ak : Av;
  const unsigned short* __restrict__ W = z == 0 ? Wq : z == 1 ? Wk : Wv;

  const int tid  = threadIdx.x;
  const int lane = tid & 63;
  const int wave = tid >> 6;        // 0..7
  const int mw   = wave >> 2;       // 0..1  (M half of the tile)
  const int nw   = wave & 3;        // 0..3  (64-col N slice)
  const int l15  = lane & 15;
  const int quad = lane >> 4;
  const int sw   = l15 & 7;

  // bijective XCD-chunked swizzle: nwg=128 per z-plane, 128%8==0.
  // XCD x owns 16 consecutive logical tiles (4 A-panels + all W ~ 4MB ~ L2).
  const int flat = blockIdx.y * 4 + blockIdx.x;      // gridDim.x == 4
  const int swz  = (flat & 7) * 16 + (flat >> 3);
  const int m0   = (swz >> 2) * 256;
  const int n0   = (swz & 3) * 256;

  const int srow8 = lane >> 3;
  const int sg    = lane & 7;

  floatx4 acc[2][2][4][2];   // [mh][nh][mi][ni]
#pragma unroll
  for (int a0 = 0; a0 < 2; a0++)
#pragma unroll
    for (int b0 = 0; b0 < 2; b0++)
#pragma unroll
      for (int c0 = 0; c0 < 4; c0++)
#pragma unroll
        for (int d0 = 0; d0 < 2; d0++) acc[a0][b0][c0][d0] = (floatx4)0.0f;

  // stage both 128x64 halves of one operand K-tile: 4 gld16/thread.
  auto stage = [&](const unsigned short* __restrict__ S, int rb, int kt,
                   unsigned short* dst) {
#pragma unroll
    for (int h = 0; h < 2; h++)
#pragma unroll
      for (int j = 0; j < 2; j++) {
        int c = wave * 2 + j;            // 1KB chunk = 8 rows of 64
        int r = c * 8 + srow8;           // row within half, 0..127
        int G = sg ^ (r & 7);            // pre-swizzled global source
        gld16(S + (size_t)(rb + h * 128 + r) * Kdim + kt + G * 8,
              dst + h * 8192 + c * 512);
      }
  };
  auto ldA = [&](int par, int mh, short8 (&a)[4][2]) {
    const unsigned short* base = &As[par][mw][0];
#pragma unroll
    for (int mi = 0; mi < 4; mi++) {
      const unsigned short* rp = base + (mh * 64 + mi * 16 + l15) * 64;
#pragma unroll
      for (int ks = 0; ks < 2; ks++)
        a[mi][ks] = *(const short8*)(rp + (((ks * 4 + quad) ^ sw) << 3));
    }
  };
  auto ldB = [&](int par, int nh, short8 (&b)[2][2]) {
    const unsigned short* base = &Bs[par][nw >> 1][0];
#pragma unroll
    for (int ni = 0; ni < 2; ni++) {
      const unsigned short* rp =
          base + ((nw & 1) * 64 + nh * 32 + ni * 16 + l15) * 64;
#pragma unroll
      for (int ks = 0; ks < 2; ks++)
        b[ni][ks] = *(const short8*)(rp + (((ks * 4 + quad) ^ sw) << 3));
    }
  };
  auto mmaq = [&](floatx4 (&c)[4][2], short8 (&a)[4][2], short8 (&b)[2][2]) {
    __builtin_amdgcn_s_setprio(1);
#pragma unroll
    for (int mi = 0; mi < 4; mi++)
#pragma unroll
      for (int ni = 0; ni < 2; ni++)
#pragma unroll
        for (int ks = 0; ks < 2; ks++)
          c[mi][ni] = __builtin_amdgcn_mfma_f32_16x16x32_bf16(
              b[ni][ks], a[mi][ks], c[mi][ni], 0, 0, 0);   // swapped: C^T
    __builtin_amdgcn_s_setprio(0);
  };

  // prologue: tiles 0 (parity 0) and 1 (parity 1); wait tile 0 resident.
  stage(A, m0, 0, &As[0][0][0]);
  stage(W, n0, 0, &Bs[0][0][0]);
  stage(A, m0, 64, &As[1][0][0]);
  stage(W, n0, 64, &Bs[1][0][0]);
  asm volatile("s_waitcnt vmcnt(8)" ::: "memory");
  bar();

  short8 a[4][2], b0[2][2], b1[2][2];
  constexpr int NT = Kdim / 64;   // 16
  for (int t = 0; t < NT; ++t) {
    const int par = t & 1;
    const int ktn = (t + 2) * 64;
    // ---- phase 1: read A(m0)[8] + B(n0)[4]; MFMA quad (0,0)
    ldA(par, 0, a);
    ldB(par, 0, b0);
    bar();
    mmaq(acc[0][0], a, b0);
    bar();
    // ---- phase 2: read B(n1)[4]; MFMA quad (0,1)
    ldB(par, 1, b1);
    bar();
    mmaq(acc[0][1], a, b1);
    bar();
    // ---- phase 3: read A(m1)[8]; issue B(t+2) (B slots freed at ph2 bar)
    ldA(par, 1, a);
    if (t < NT - 2) stage(W, n0, ktn, &Bs[par][0][0]);
    bar();
    mmaq(acc[1][0], a, b0);
    bar();
    // ---- phase 4: issue A(t+2) (A slots freed at ph3 bar); MFMA quad (1,1)
    if (t < NT - 2) stage(A, m0, ktn, &As[par][0][0]);
    bar();
    mmaq(acc[1][1], a, b1);
    // tile boundary: counted vmcnt — newest 8 loads = tile t+2's; everything
    // older (incl. tile t+1) is resident. Drain fully only entering last tile.
    if (t < NT - 2)
      asm volatile("s_waitcnt vmcnt(8)" ::: "memory");
    else if (t == NT - 2)
      asm volatile("s_waitcnt vmcnt(0)" ::: "memory");
    bar();
  }

  // Epilogue. C^T: frag rows (quad*4+r) = n (dh), frag col (l15) = m (t).
  const int gmb = m0 + mw * 128;
  const int gnb = n0 + nw * 64;
#pragma unroll
  for (int mh = 0; mh < 2; mh++)
#pragma unroll
    for (int mi = 0; mi < 4; mi++) {
      int t_abs = gmb + mh * 64 + mi * 16 + l15;
      int b = t_abs >> 11, tb = t_abs & (Tseq - 1);
#pragma unroll
      for (int nh = 0; nh < 2; nh++)
#pragma unroll
        for (int ni = 0; ni < 2; ni++) {
          int gn0 = gnb + nh * 32 + ni * 16 + quad * 4;
          int h = gn0 >> 6, dh0 = gn0 & 63;
          size_t base = ((size_t)((b * NH + h) * Tseq + tb)) * 64 + dh0;
          floatx4 v = acc[mh][nh][mi][ni];
          if (z == 0) {
            ushort4 w = {f2b(v[0]), f2b(v[1]), f2b(v[2]), f2b(v[3])};
            *(ushort4*)(Qh + base) = w;
          } else if (z == 1) {
            *(float4*)(Kout + base) = *(float4*)&v;
            ushort4 w = {f2b(v[0]), f2b(v[1]), f2b(v[2]), f2b(v[3])};
            *(ushort4*)(Kh + base) = w;
          } else {
            *(float4*)(Vout + base) = *(float4*)&v;
            size_t vtb = ((size_t)((b * NH + h) * 64 + dh0)) * Tseq + tb;
#pragma unroll
            for (int r = 0; r < 4; r++)
              VTg[vtb + (size_t)r * Tseq] = f2b(v[r]);   // 16-lane 32B segments
          }
        }
    }
}

// ---------------------------------------------------------------- O GEMM
// out[M,N] f32 = Og[M,K] bf16 * Wo[N,K]^T bf16.  128² 2-phase structure
// (unchanged this round — isolate the QKV A/B).
__launch_bounds__(256)
__global__ void gemm_o(const unsigned short* __restrict__ A,
                       const unsigned short* __restrict__ W,
                       float* __restrict__ Cf) {
  __shared__ __align__(16) unsigned short As[128 * 64];
  __shared__ __align__(16) unsigned short Bs[128 * 64];

  const int tid  = threadIdx.x;
  const int lane = tid & 63;
  const int wave = tid >> 6;
  const int l15  = lane & 15;
  const int quad = lane >> 4;
  const int sw   = l15 & 7;
  const int m0 = blockIdx.y * 128;
  const int n0 = blockIdx.x * 128;
  const int wm = (wave >> 1) * 64;
  const int wn = (wave & 1) * 64;

  floatx4 acc[4][4];
  for (int i = 0; i < 4; i++)
    for (int j = 0; j < 4; j++) acc[i][j] = (floatx4)0.0f;

  const int srow8 = lane >> 3;
  const int sg    = lane & 7;

  for (int kt = 0; kt < Kdim; kt += 64) {
    for (int jj = 0; jj < 4; jj++) {
      int cc = wave * 4 + jj;
      int row = cc * 8 + srow8;
      int G = sg ^ (row & 7);
      gld16(A + (size_t)(m0 + row) * Kdim + kt + G * 8, As + cc * 512);
      gld16(W + (size_t)(n0 + row) * Kdim + kt + G * 8, Bs + cc * 512);
    }
    __syncthreads();

    for (int hf = 0; hf < 2; hf++) {
      short8 af[4], bw[4];
      for (int mi = 0; mi < 4; mi++)
        af[mi] = *(const short8*)(As + (wm + mi * 16 + l15) * 64 +
                                  (((hf * 4 + quad) ^ sw) << 3));
      for (int ni = 0; ni < 4; ni++)
        bw[ni] = *(const short8*)(Bs + (wn + ni * 16 + l15) * 64 +
                                  (((hf * 4 + quad) ^ sw) << 3));
      for (int mi = 0; mi < 4; mi++)
        for (int ni = 0; ni < 4; ni++)
          acc[mi][ni] = __builtin_amdgcn_mfma_f32_16x16x32_bf16(
              bw[ni], af[mi], acc[mi][ni], 0, 0, 0);
    }
    __syncthreads();
  }

  for (int mi = 0; mi < 4; mi++) {
    int t_abs = m0 + wm + mi * 16 + l15;
    for (int ni = 0; ni < 4; ni++) {
      int gn0 = n0 + wn + ni * 16 + quad * 4;
      floatx4 v = acc[mi][ni];
      *(float4*)(Cf + (size_t)t_abs * Ndim + gn0) = *(float4*)&v;
    }
  }
}

// ---------------------------------------------------------------- attention
// Causal flash attention, S^T formulation. One block per (b*H+h, q-tile 128);
// qt = 15 - blockIdx.y -> longest blocks dispatch first (no occupancy tail).
__launch_bounds__(256)
__global__ void attn_k(const unsigned short* __restrict__ Qh,
                       const unsigned short* __restrict__ Kh,
                       const unsigned short* __restrict__ VTg,
                       unsigned short* __restrict__ Og) {
  __shared__ __align__(16) unsigned short Kt[64 * 64];
  __shared__ __align__(16) unsigned short Vt[64 * 64];
  __shared__ __align__(16) unsigned short Pl[128 * 64];

  const int tid  = threadIdx.x;
  const int lane = tid & 63;
  const int wave = tid >> 6;
  const int l15  = lane & 15;
  const int quad = lane >> 4;
  const int sw   = l15 & 7;
  const int bh = blockIdx.x;
  const int qt = 15 - blockIdx.y;

  const size_t headoff = (size_t)bh * Tseq * 64;
  const int qbase = qt * 128 + wave * 32;

  short8 bq[2][2];
  for (int m = 0; m < 2; m++)
    for (int hf = 0; hf < 2; hf++)
      bq[m][hf] = *(const short8*)(Qh + headoff +
                                   (size_t)(qbase + m * 16 + l15) * 64 + hf * 32 + quad * 8);

  floatx4 o[2][4];
  for (int m = 0; m < 2; m++)
    for (int nb = 0; nb < 4; nb++) o[m][nb] = (floatx4)0.0f;
  float mrow[2] = {-INFINITY, -INFINITY};
  float lrow[2] = {0.0f, 0.0f};

  const int srow8 = lane >> 3;
  const int sg    = lane & 7;
  const int nkt   = 2 * qt + 2;
  const float kscale = 0.18033688011112042f;  // (1/8) * log2(e)

  for (int kt = 0; kt < nkt; kt++) {
    const int k0 = kt * 64;
    for (int jj = 0; jj < 2; jj++) {
      int cc = wave * 2 + jj;
      int row = cc * 8 + srow8;
      int G = sg ^ (row & 7);
      gld16(Kh + headoff + (size_t)(k0 + row) * 64 + G * 8, Kt + cc * 512);
      gld16(VTg + ((size_t)bh * 64 + row) * Tseq + k0 + G * 8, Vt + cc * 512);
    }
    __syncthreads();

    floatx4 st[2][4];
    for (int nb = 0; nb < 4; nb++) {
      const unsigned short* kr = Kt + (nb * 16 + l15) * 64;
      short8 ak0 = *(const short8*)(kr + ((quad ^ sw) << 3));
      short8 ak1 = *(const short8*)(kr + (((quad + 4) ^ sw) << 3));
      for (int m = 0; m < 2; m++) {
        floatx4 a = (floatx4)0.0f;
        a = __builtin_amdgcn_mfma_f32_16x16x32_bf16(ak0, bq[m][0], a, 0, 0, 0);
        a = __builtin_amdgcn_mfma_f32_16x16x32_bf16(ak1, bq[m][1], a, 0, 0, 0);
        st[m][nb] = a;
      }
    }

    if (k0 + 63 > qbase) {
      for (int m = 0; m < 2; m++) {
        int qg = qbase + m * 16 + l15;
        for (int nb = 0; nb < 4; nb++)
          for (int r = 0; r < 4; r++) {
            int kg = k0 + nb * 16 + quad * 4 + r;
            if (kg > qg) st[m][nb][r] = -INFINITY;
          }
      }
    }

    for (int m = 0; m < 2; m++) {
      float mt = fmaxf(fmaxf(st[m][0][0], st[m][0][1]), fmaxf(st[m][0][2], st[m][0][3]));
      for (int nb = 1; nb < 4; nb++)
        mt = fmaxf(mt, fmaxf(fmaxf(st[m][nb][0], st[m][nb][1]),
                             fmaxf(st[m][nb][2], st[m][nb][3])));
      mt = fmaxf(mt, __shfl_xor(mt, 16, 64));
      mt = fmaxf(mt, __shfl_xor(mt, 32, 64));
      float mnew = fmaxf(mrow[m], mt);
      float al = __builtin_amdgcn_exp2f((mrow[m] - mnew) * kscale);
      mrow[m] = mnew;
      const float ms = mnew * kscale;

      float rs = 0.0f;
      const int prow = (wave * 32 + m * 16 + l15) * 64;
      for (int nb = 0; nb < 4; nb++) {
        float p0 = __builtin_amdgcn_exp2f(__builtin_fmaf(st[m][nb][0], kscale, -ms));
        float p1 = __builtin_amdgcn_exp2f(__builtin_fmaf(st[m][nb][1], kscale, -ms));
        float p2 = __builtin_amdgcn_exp2f(__builtin_fmaf(st[m][nb][2], kscale, -ms));
        float p3 = __builtin_amdgcn_exp2f(__builtin_fmaf(st[m][nb][3], kscale, -ms));
        rs += (p0 + p1) + (p2 + p3);
        uint2 w = {pk2(p0, p1), pk2(p2, p3)};
        int klb = nb * 16 + quad * 4;
        int colp = (((klb >> 3) ^ sw) << 3) | (klb & 7);
        *(uint2*)(Pl + prow + colp) = w;
      }
      rs += __shfl_xor(rs, 16, 64);
      rs += __shfl_xor(rs, 32, 64);
      lrow[m] = lrow[m] * al + rs;
      for (int nb = 0; nb < 4; nb++)
        for (int r = 0; r < 4; r++) o[m][nb][r] *= al;
    }

    short8 av[4][2];
    for (int nb = 0; nb < 4; nb++) {
      const unsigned short* vr = Vt + (nb * 16 + l15) * 64;
      av[nb][0] = *(const short8*)(vr + ((quad ^ sw) << 3));
      av[nb][1] = *(const short8*)(vr + (((quad + 4) ^ sw) << 3));
    }
    for (int m = 0; m < 2; m++) {
      const unsigned short* pr = Pl + (wave * 32 + m * 16 + l15) * 64;
      short8 bp0 = *(const short8*)(pr + ((quad ^ sw) << 3));
      short8 bp1 = *(const short8*)(pr + (((quad + 4) ^ sw) << 3));
      for (int nb = 0; nb < 4; nb++) {
        o[m][nb] = __builtin_amdgcn_mfma_f32_16x16x32_bf16(av[nb][0], bp0, o[m][nb], 0, 0, 0);
        o[m][nb] = __builtin_amdgcn_mfma_f32_16x16x32_bf16(av[nb][1], bp1, o[m][nb], 0, 0, 0);
      }
    }
    __syncthreads();
  }

  const int b = bh >> 4, h = bh & 15;
  for (int m = 0; m < 2; m++) {
    float inv = 1.0f / lrow[m];
    int q = qbase + m * 16 + l15;
    size_t rowoff = ((size_t)(b * Tseq + q)) * 1024 + h * 64;
    for (int nb = 0; nb < 4; nb++) {
      ushort4 w;
      w.x = f2b(o[m][nb][0] * inv);
      w.y = f2b(o[m][nb][1] * inv);
      w.z = f2b(o[m][nb][2] * inv);
      w.w = f2b(o[m][nb][3] * inv);
      *(ushort4*)(Og + rowoff + nb * 16 + quad * 4) = w;
    }
  }
}

// ---------------------------------------------------------------- launcher
extern "C" void kernel_launch(void* const* d_in, const int* in_sizes, int n_in,
                              void* d_out, int out_size, void* d_ws, size_t ws_size,
                              hipStream_t stream) {
  const float* q  = (const float*)d_in[0];
  const float* k  = (const float*)d_in[1];
  const float* v  = (const float*)d_in[2];
  const float* wq = (const float*)d_in[3];
  const float* wk = (const float*)d_in[4];
  const float* wv = (const float*)d_in[5];
  const float* wo = (const float*)d_in[6];
  // d_in[7] = attn_mask: deterministically causal; handled analytically.
  float* out = (float*)d_out;

  constexpr size_t BTD = (size_t)Mdim * Kdim;
  constexpr size_t DD  = (size_t)Ndim * Kdim;
  constexpr size_t MB16 = BTD * 2;

  char* ws = (char*)d_ws;
  unsigned short* Qh  = (unsigned short*)(ws);
  unsigned short* Kh  = (unsigned short*)(ws + MB16);
  unsigned short* VTg = (unsigned short*)(ws + 2 * MB16);
  unsigned short* Og  = (unsigned short*)(ws + 3 * MB16);
  unsigned short* qb  = (unsigned short*)(ws + 4 * MB16);
  unsigned short* kb  = (unsigned short*)(ws + 5 * MB16);
  unsigned short* vb  = (unsigned short*)(ws + 6 * MB16);
  unsigned short* wqb = (unsigned short*)(ws + 7 * MB16);
  unsigned short* wkb = wqb + DD;
  unsigned short* wvb = wkb + DD;
  unsigned short* wob = wvb + DD;

  float* Kout = out + BTD;
  float* Vout = out + 2 * BTD;

  cast_k<<<dim3(4096, 7), 256, 0, stream>>>(q, k, v, wq, wk, wv, wo,
                                            qb, kb, vb, wqb, wkb, wvb, wob);

  gemm_qkv<<<dim3(Ndim / 256, Mdim / 256, 3), 512, 0, stream>>>(
      qb, kb, vb, wqb, wkb, wvb, Qh, Kh, Kout, VTg, Vout);

  attn_k<<<dim3(4 * NH, Tseq / 128), 256, 0, stream>>>(Qh, Kh, VTg, Og);

  gemm_o<<<dim3(Ndim / 128, Mdim / 128), 256, 0, stream>>>(Og, wob, out);
}

// Round 2
// 366.664 us; speedup vs baseline: 1.0497x; 1.0143x over previous
//
#include <hip/hip_runtime.h>
#include <hip/hip_bf16.h>
#include <math.h>

// Problem constants: B=4, T=2048, D=1024, H=16, DH=64
constexpr int Mdim = 8192;   // B*T
constexpr int Ndim = 1024;
constexpr int Kdim = 1024;
constexpr int Tseq = 2048;
constexpr int NH   = 16;

typedef __attribute__((ext_vector_type(8))) short short8;   // 8 bf16 = 4 VGPRs
typedef __attribute__((ext_vector_type(4))) float floatx4;  // MFMA C/D frag

__device__ __forceinline__ unsigned short f2b(float f) {   // RNE
  unsigned int x = __builtin_bit_cast(unsigned int, f);
  x += 0x7fffu + ((x >> 16) & 1u);
  return (unsigned short)(x >> 16);
}
__device__ __forceinline__ unsigned int pk2(float a, float b) {  // fast 2xbf16
  unsigned int ua = __builtin_bit_cast(unsigned int, a) + 0x8000u;
  unsigned int ub = __builtin_bit_cast(unsigned int, b) + 0x8000u;
  return (ua >> 16) | (ub & 0xffff0000u);
}
// async global->LDS, 16B per lane; LDS dest = uniform base + lane*16
__device__ __forceinline__ void gld16(const void* g, const void* l) {
  __builtin_amdgcn_global_load_lds(
      (const __attribute__((address_space(1))) unsigned int*)(unsigned long long)g,
      (__attribute__((address_space(3))) unsigned int*)(unsigned int)(unsigned long long)l,
      16, 0, 0);
}
// raw barrier (no vmcnt drain) with compiler-level memory fences so C++ LDS
// reads / gld16 issues cannot migrate across phases.
__device__ __forceinline__ void bar() {
  asm volatile("" ::: "memory");
  __builtin_amdgcn_s_barrier();
  asm volatile("" ::: "memory");
}

// ---------------------------------------------------------------- casts
__global__ __launch_bounds__(256) void cast_k(
    const float* __restrict__ q, const float* __restrict__ k,
    const float* __restrict__ v, const float* __restrict__ wq,
    const float* __restrict__ wk, const float* __restrict__ wv,
    const float* __restrict__ wo,
    unsigned short* d0, unsigned short* d1, unsigned short* d2,
    unsigned short* d3, unsigned short* d4, unsigned short* d5,
    unsigned short* d6) {
  int y = blockIdx.y;
  const float* s = y == 0 ? q : y == 1 ? k : y == 2 ? v
                 : y == 3 ? wq : y == 4 ? wk : y == 5 ? wv : wo;
  unsigned short* d = y == 0 ? d0 : y == 1 ? d1 : y == 2 ? d2
                    : y == 3 ? d3 : y == 4 ? d4 : y == 5 ? d5 : d6;
  size_t n = (y < 3) ? (size_t)Mdim * Kdim : (size_t)Ndim * Kdim;
  size_t i = ((size_t)blockIdx.x * 256 + threadIdx.x) * 8;
  if (i >= n) return;
  float4 a = *(const float4*)(s + i);
  float4 b = *(const float4*)(s + i + 4);
  uint4 w;
  w.x = (unsigned)f2b(a.x) | ((unsigned)f2b(a.y) << 16);
  w.y = (unsigned)f2b(a.z) | ((unsigned)f2b(a.w) << 16);
  w.z = (unsigned)f2b(b.x) | ((unsigned)f2b(b.y) << 16);
  w.w = (unsigned)f2b(b.z) | ((unsigned)f2b(b.w) << 16);
  *(uint4*)(d + i) = w;
}

// ---------------------------------------------------------------- QKV GEMM
// 256x256 tile, BK=64, 8 waves (2M x 4N), 512 threads — 8-phase schedule
// (T3+T4 counted vmcnt + T5 setprio on top of T2 XOR swizzle).
// (unchanged this round — isolating the attn_k A/B; its counters weren't
// visible this round, tail/occupancy fix pending counter evidence.)
__launch_bounds__(512, 2)
__global__ void gemm_qkv(const unsigned short* __restrict__ Aq,
                         const unsigned short* __restrict__ Ak,
                         const unsigned short* __restrict__ Av,
                         const unsigned short* __restrict__ Wq,
                         const unsigned short* __restrict__ Wk,
                         const unsigned short* __restrict__ Wv,
                         unsigned short* __restrict__ Qh,
                         unsigned short* __restrict__ Kh,
                         float* __restrict__ Kout,
                         unsigned short* __restrict__ VTg,
                         float* __restrict__ Vout) {
  __shared__ __align__(16) unsigned short As[2][2][8192];  // [par][half][128*64]
  __shared__ __align__(16) unsigned short Bs[2][2][8192];

  const int z = blockIdx.z;
  const unsigned short* __restrict__ A = z == 0 ? Aq : z == 1 ? Ak : Av;
  const unsigned short* __restrict__ W = z == 0 ? Wq : z == 1 ? Wk : Wv;

  const int tid  = threadIdx.x;
  const int lane = tid & 63;
  const int wave = tid >> 6;        // 0..7
  const int mw   = wave >> 2;       // 0..1  (M half of the tile)
  const int nw   = wave & 3;        // 0..3  (64-col N slice)
  const int l15  = lane & 15;
  const int quad = lane >> 4;
  const int sw   = l15 & 7;

  // bijective XCD-chunked swizzle: nwg=128 per z-plane, 128%8==0.
  const int flat = blockIdx.y * 4 + blockIdx.x;      // gridDim.x == 4
  const int swz  = (flat & 7) * 16 + (flat >> 3);
  const int m0   = (swz >> 2) * 256;
  const int n0   = (swz & 3) * 256;

  const int srow8 = lane >> 3;
  const int sg    = lane & 7;

  floatx4 acc[2][2][4][2];   // [mh][nh][mi][ni]
#pragma unroll
  for (int a0 = 0; a0 < 2; a0++)
#pragma unroll
    for (int b0 = 0; b0 < 2; b0++)
#pragma unroll
      for (int c0 = 0; c0 < 4; c0++)
#pragma unroll
        for (int d0 = 0; d0 < 2; d0++) acc[a0][b0][c0][d0] = (floatx4)0.0f;

  auto stage = [&](const unsigned short* __restrict__ S, int rb, int kt,
                   unsigned short* dst) {
#pragma unroll
    for (int h = 0; h < 2; h++)
#pragma unroll
      for (int j = 0; j < 2; j++) {
        int c = wave * 2 + j;            // 1KB chunk = 8 rows of 64
        int r = c * 8 + srow8;           // row within half, 0..127
        int G = sg ^ (r & 7);            // pre-swizzled global source
        gld16(S + (size_t)(rb + h * 128 + r) * Kdim + kt + G * 8,
              dst + h * 8192 + c * 512);
      }
  };
  auto ldA = [&](int par, int mh, short8 (&a)[4][2]) {
    const unsigned short* base = &As[par][mw][0];
#pragma unroll
    for (int mi = 0; mi < 4; mi++) {
      const unsigned short* rp = base + (mh * 64 + mi * 16 + l15) * 64;
#pragma unroll
      for (int ks = 0; ks < 2; ks++)
        a[mi][ks] = *(const short8*)(rp + (((ks * 4 + quad) ^ sw) << 3));
    }
  };
  auto ldB = [&](int par, int nh, short8 (&b)[2][2]) {
    const unsigned short* base = &Bs[par][nw >> 1][0];
#pragma unroll
    for (int ni = 0; ni < 2; ni++) {
      const unsigned short* rp =
          base + ((nw & 1) * 64 + nh * 32 + ni * 16 + l15) * 64;
#pragma unroll
      for (int ks = 0; ks < 2; ks++)
        b[ni][ks] = *(const short8*)(rp + (((ks * 4 + quad) ^ sw) << 3));
    }
  };
  auto mmaq = [&](floatx4 (&c)[4][2], short8 (&a)[4][2], short8 (&b)[2][2]) {
    __builtin_amdgcn_s_setprio(1);
#pragma unroll
    for (int mi = 0; mi < 4; mi++)
#pragma unroll
      for (int ni = 0; ni < 2; ni++)
#pragma unroll
        for (int ks = 0; ks < 2; ks++)
          c[mi][ni] = __builtin_amdgcn_mfma_f32_16x16x32_bf16(
              b[ni][ks], a[mi][ks], c[mi][ni], 0, 0, 0);   // swapped: C^T
    __builtin_amdgcn_s_setprio(0);
  };

  // prologue: tiles 0 (parity 0) and 1 (parity 1); wait tile 0 resident.
  stage(A, m0, 0, &As[0][0][0]);
  stage(W, n0, 0, &Bs[0][0][0]);
  stage(A, m0, 64, &As[1][0][0]);
  stage(W, n0, 64, &Bs[1][0][0]);
  asm volatile("s_waitcnt vmcnt(8)" ::: "memory");
  bar();

  short8 a[4][2], b0[2][2], b1[2][2];
  constexpr int NT = Kdim / 64;   // 16
  for (int t = 0; t < NT; ++t) {
    const int par = t & 1;
    const int ktn = (t + 2) * 64;
    // ---- phase 1: read A(m0)[8] + B(n0)[4]; MFMA quad (0,0)
    ldA(par, 0, a);
    ldB(par, 0, b0);
    bar();
    mmaq(acc[0][0], a, b0);
    bar();
    // ---- phase 2: read B(n1)[4]; MFMA quad (0,1)
    ldB(par, 1, b1);
    bar();
    mmaq(acc[0][1], a, b1);
    bar();
    // ---- phase 3: read A(m1)[8]; issue B(t+2) (B slots freed at ph2 bar)
    ldA(par, 1, a);
    if (t < NT - 2) stage(W, n0, ktn, &Bs[par][0][0]);
    bar();
    mmaq(acc[1][0], a, b0);
    bar();
    // ---- phase 4: issue A(t+2) (A slots freed at ph3 bar); MFMA quad (1,1)
    if (t < NT - 2) stage(A, m0, ktn, &As[par][0][0]);
    bar();
    mmaq(acc[1][1], a, b1);
    if (t < NT - 2)
      asm volatile("s_waitcnt vmcnt(8)" ::: "memory");
    else if (t == NT - 2)
      asm volatile("s_waitcnt vmcnt(0)" ::: "memory");
    bar();
  }

  // Epilogue. C^T: frag rows (quad*4+r) = n (dh), frag col (l15) = m (t).
  const int gmb = m0 + mw * 128;
  const int gnb = n0 + nw * 64;
#pragma unroll
  for (int mh = 0; mh < 2; mh++)
#pragma unroll
    for (int mi = 0; mi < 4; mi++) {
      int t_abs = gmb + mh * 64 + mi * 16 + l15;
      int b = t_abs >> 11, tb = t_abs & (Tseq - 1);
#pragma unroll
      for (int nh = 0; nh < 2; nh++)
#pragma unroll
        for (int ni = 0; ni < 2; ni++) {
          int gn0 = gnb + nh * 32 + ni * 16 + quad * 4;
          int h = gn0 >> 6, dh0 = gn0 & 63;
          size_t base = ((size_t)((b * NH + h) * Tseq + tb)) * 64 + dh0;
          floatx4 v = acc[mh][nh][mi][ni];
          if (z == 0) {
            ushort4 w = {f2b(v[0]), f2b(v[1]), f2b(v[2]), f2b(v[3])};
            *(ushort4*)(Qh + base) = w;
          } else if (z == 1) {
            *(float4*)(Kout + base) = *(float4*)&v;
            ushort4 w = {f2b(v[0]), f2b(v[1]), f2b(v[2]), f2b(v[3])};
            *(ushort4*)(Kh + base) = w;
          } else {
            *(float4*)(Vout + base) = *(float4*)&v;
            size_t vtb = ((size_t)((b * NH + h) * 64 + dh0)) * Tseq + tb;
#pragma unroll
            for (int r = 0; r < 4; r++)
              VTg[vtb + (size_t)r * Tseq] = f2b(v[r]);   // 16-lane 32B segments
          }
        }
    }
}

// ---------------------------------------------------------------- O GEMM
// out[M,N] f32 = Og[M,K] bf16 * Wo[N,K]^T bf16.  128² 2-phase structure
// (unchanged this round).
__launch_bounds__(256)
__global__ void gemm_o(const unsigned short* __restrict__ A,
                       const unsigned short* __restrict__ W,
                       float* __restrict__ Cf) {
  __shared__ __align__(16) unsigned short As[128 * 64];
  __shared__ __align__(16) unsigned short Bs[128 * 64];

  const int tid  = threadIdx.x;
  const int lane = tid & 63;
  const int wave = tid >> 6;
  const int l15  = lane & 15;
  const int quad = lane >> 4;
  const int sw   = l15 & 7;
  const int m0 = blockIdx.y * 128;
  const int n0 = blockIdx.x * 128;
  const int wm = (wave >> 1) * 64;
  const int wn = (wave & 1) * 64;

  floatx4 acc[4][4];
  for (int i = 0; i < 4; i++)
    for (int j = 0; j < 4; j++) acc[i][j] = (floatx4)0.0f;

  const int srow8 = lane >> 3;
  const int sg    = lane & 7;

  for (int kt = 0; kt < Kdim; kt += 64) {
    for (int jj = 0; jj < 4; jj++) {
      int cc = wave * 4 + jj;
      int row = cc * 8 + srow8;
      int G = sg ^ (row & 7);
      gld16(A + (size_t)(m0 + row) * Kdim + kt + G * 8, As + cc * 512);
      gld16(W + (size_t)(n0 + row) * Kdim + kt + G * 8, Bs + cc * 512);
    }
    __syncthreads();

    for (int hf = 0; hf < 2; hf++) {
      short8 af[4], bw[4];
      for (int mi = 0; mi < 4; mi++)
        af[mi] = *(const short8*)(As + (wm + mi * 16 + l15) * 64 +
                                  (((hf * 4 + quad) ^ sw) << 3));
      for (int ni = 0; ni < 4; ni++)
        bw[ni] = *(const short8*)(Bs + (wn + ni * 16 + l15) * 64 +
                                  (((hf * 4 + quad) ^ sw) << 3));
      for (int mi = 0; mi < 4; mi++)
        for (int ni = 0; ni < 4; ni++)
          acc[mi][ni] = __builtin_amdgcn_mfma_f32_16x16x32_bf16(
              bw[ni], af[mi], acc[mi][ni], 0, 0, 0);
    }
    __syncthreads();
  }

  for (int mi = 0; mi < 4; mi++) {
    int t_abs = m0 + wm + mi * 16 + l15;
    for (int ni = 0; ni < 4; ni++) {
      int gn0 = n0 + wn + ni * 16 + quad * 4;
      floatx4 v = acc[mi][ni];
      *(float4*)(Cf + (size_t)t_abs * Ndim + gn0) = *(float4*)&v;
    }
  }
}

// ---------------------------------------------------------------- attention
// Causal flash attention, S^T formulation. QBLK=64 (4 waves x 16 q-rows),
// KVBLK=64 double-buffered. One block handles the q-tile PAIR (31-p, p):
// every block = exactly 33 kv-iters -> perfect balance, no drain tail.
// LDS 40KB -> 4 blocks/CU resident (16 waves/CU vs 8 before). Per iter:
// issue next K/V stage FIRST, compute tile t, then vmcnt(0)+barrier — the
// stage latency hides under QK^T+softmax+PV (one barrier/iter, no
// stage-then-stall). Defer-max (T13, THR=8 log2-units): skip the o/l
// rescale pass when the whole wave's per-tile max growth is small
// (P bounded by 2^8; f32 l-sum and bf16 P have ample headroom).
__launch_bounds__(256)
__global__ void attn_k(const unsigned short* __restrict__ Qh,
                       const unsigned short* __restrict__ Kh,
                       const unsigned short* __restrict__ VTg,
                       unsigned short* __restrict__ Og) {
  __shared__ __align__(16) unsigned short Kt[2][64 * 64];
  __shared__ __align__(16) unsigned short Vt[2][64 * 64];
  __shared__ __align__(16) unsigned short Pl[64 * 64];

  const int tid  = threadIdx.x;
  const int lane = tid & 63;
  const int wave = tid >> 6;
  const int l15  = lane & 15;
  const int quad = lane >> 4;
  const int sw   = l15 & 7;
  const int bh   = blockIdx.x;

  const size_t headoff = (size_t)bh * Tseq * 64;
  const int srow8 = lane >> 3;
  const int sg    = lane & 7;
  const float kscale = 0.18033688011112042f;  // (1/8) * log2(e)
  const int b = bh >> 4, h = bh & 15;

  for (int half = 0; half < 2; half++) {
    const int a   = half ? blockIdx.y : 31 - blockIdx.y;  // 64-row q-tile idx
    const int nkt = a + 1;
    const int qg  = a * 64 + wave * 16 + l15;   // this lane's q row

    short8 bq[2];
#pragma unroll
    for (int hf = 0; hf < 2; hf++)
      bq[hf] = *(const short8*)(Qh + headoff + (size_t)qg * 64 +
                                hf * 32 + quad * 8);

    floatx4 o[4];
#pragma unroll
    for (int nb = 0; nb < 4; nb++) o[nb] = (floatx4)0.0f;
    float mrow = -INFINITY, lrow = 0.0f;

    auto stage = [&](int par, int kt) {
      const int k0 = kt * 64;
#pragma unroll
      for (int jj = 0; jj < 2; jj++) {
        int cc  = wave * 2 + jj;
        int row = cc * 8 + srow8;
        int G   = sg ^ (row & 7);
        gld16(Kh + headoff + (size_t)(k0 + row) * 64 + G * 8,
              &Kt[par][cc * 512]);
        gld16(VTg + ((size_t)bh * 64 + row) * Tseq + k0 + G * 8,
              &Vt[par][cc * 512]);
      }
    };

    stage(0, 0);
    asm volatile("s_waitcnt vmcnt(0)" ::: "memory");
    bar();

    for (int kt = 0; kt < nkt; kt++) {
      const int par = kt & 1;
      if (kt + 1 < nkt) stage(par ^ 1, kt + 1);   // prefetch hides under compute
      const int k0 = kt * 64;

      // QK^T (S^T frag: lane l15 = q-row, quad*4+r (+16nb) = k)
      floatx4 st[4];
#pragma unroll
      for (int nb = 0; nb < 4; nb++) {
        const unsigned short* kr = &Kt[par][(nb * 16 + l15) * 64];
        short8 ak0 = *(const short8*)(kr + ((quad ^ sw) << 3));
        short8 ak1 = *(const short8*)(kr + (((quad + 4) ^ sw) << 3));
        floatx4 acc0 = (floatx4)0.0f;
        acc0 = __builtin_amdgcn_mfma_f32_16x16x32_bf16(ak0, bq[0], acc0, 0, 0, 0);
        acc0 = __builtin_amdgcn_mfma_f32_16x16x32_bf16(ak1, bq[1], acc0, 0, 0, 0);
        st[nb] = acc0;
      }

      if (kt == nkt - 1) {   // only the diagonal tile needs masking
#pragma unroll
        for (int nb = 0; nb < 4; nb++)
#pragma unroll
          for (int r = 0; r < 4; r++) {
            int kg = k0 + nb * 16 + quad * 4 + r;
            if (kg > qg) st[nb][r] = -INFINITY;
          }
      }

      // row max (wave-parallel: quad lanes hold the row's 4 k-chunks)
      float mt = fmaxf(fmaxf(st[0][0], st[0][1]), fmaxf(st[0][2], st[0][3]));
#pragma unroll
      for (int nb = 1; nb < 4; nb++)
        mt = fmaxf(mt, fmaxf(fmaxf(st[nb][0], st[nb][1]),
                             fmaxf(st[nb][2], st[nb][3])));
      mt = fmaxf(mt, __shfl_xor(mt, 16, 64));
      mt = fmaxf(mt, __shfl_xor(mt, 32, 64));

      // T13 defer-max: skip rescale while growth <= 8 log2-units (P <= 2^8)
      if (!__all((mt - mrow) * kscale <= 8.0f)) {
        float mnew = fmaxf(mrow, mt);
        float al = __builtin_amdgcn_exp2f((mrow - mnew) * kscale);
        mrow = mnew;
        lrow *= al;
#pragma unroll
        for (int nb = 0; nb < 4; nb++)
#pragma unroll
          for (int r = 0; r < 4; r++) o[nb][r] *= al;
      }
      const float ms = mrow * kscale;

      float rs = 0.0f;
      const int prow = (wave * 16 + l15) * 64;
#pragma unroll
      for (int nb = 0; nb < 4; nb++) {
        float p0 = __builtin_amdgcn_exp2f(__builtin_fmaf(st[nb][0], kscale, -ms));
        float p1 = __builtin_amdgcn_exp2f(__builtin_fmaf(st[nb][1], kscale, -ms));
        float p2 = __builtin_amdgcn_exp2f(__builtin_fmaf(st[nb][2], kscale, -ms));
        float p3 = __builtin_amdgcn_exp2f(__builtin_fmaf(st[nb][3], kscale, -ms));
        rs += (p0 + p1) + (p2 + p3);
        uint2 w = {pk2(p0, p1), pk2(p2, p3)};
        int klb = nb * 16 + quad * 4;
        int colp = (((klb >> 3) ^ sw) << 3) | (klb & 7);
        *(uint2*)(Pl + prow + colp) = w;
      }
      rs += __shfl_xor(rs, 16, 64);
      rs += __shfl_xor(rs, 32, 64);
      lrow += rs;

      // PV
      short8 av[4][2];
#pragma unroll
      for (int nb = 0; nb < 4; nb++) {
        const unsigned short* vr = &Vt[par][(nb * 16 + l15) * 64];
        av[nb][0] = *(const short8*)(vr + ((quad ^ sw) << 3));
        av[nb][1] = *(const short8*)(vr + (((quad + 4) ^ sw) << 3));
      }
      const unsigned short* pr = Pl + prow;
      short8 bp0 = *(const short8*)(pr + ((quad ^ sw) << 3));
      short8 bp1 = *(const short8*)(pr + (((quad + 4) ^ sw) << 3));
#pragma unroll
      for (int nb = 0; nb < 4; nb++) {
        o[nb] = __builtin_amdgcn_mfma_f32_16x16x32_bf16(av[nb][0], bp0, o[nb], 0, 0, 0);
        o[nb] = __builtin_amdgcn_mfma_f32_16x16x32_bf16(av[nb][1], bp1, o[nb], 0, 0, 0);
      }

      // wait own prefetch; barrier publishes all waves' stages for next iter
      asm volatile("s_waitcnt vmcnt(0)" ::: "memory");
      bar();
    }

    float inv = 1.0f / lrow;
    size_t rowoff = ((size_t)(b * Tseq + qg)) * 1024 + h * 64;
#pragma unroll
    for (int nb = 0; nb < 4; nb++) {
      ushort4 w;
      w.x = f2b(o[nb][0] * inv);
      w.y = f2b(o[nb][1] * inv);
      w.z = f2b(o[nb][2] * inv);
      w.w = f2b(o[nb][3] * inv);
      *(ushort4*)(Og + rowoff + nb * 16 + quad * 4) = w;
    }
  }
}

// ---------------------------------------------------------------- launcher
extern "C" void kernel_launch(void* const* d_in, const int* in_sizes, int n_in,
                              void* d_out, int out_size, void* d_ws, size_t ws_size,
                              hipStream_t stream) {
  const float* q  = (const float*)d_in[0];
  const float* k  = (const float*)d_in[1];
  const float* v  = (const float*)d_in[2];
  const float* wq = (const float*)d_in[3];
  const float* wk = (const float*)d_in[4];
  const float* wv = (const float*)d_in[5];
  const float* wo = (const float*)d_in[6];
  // d_in[7] = attn_mask: deterministically causal; handled analytically.
  float* out = (float*)d_out;

  constexpr size_t BTD = (size_t)Mdim * Kdim;
  constexpr size_t DD  = (size_t)Ndim * Kdim;
  constexpr size_t MB16 = BTD * 2;

  char* ws = (char*)d_ws;
  unsigned short* Qh  = (unsigned short*)(ws);
  unsigned short* Kh  = (unsigned short*)(ws + MB16);
  unsigned short* VTg = (unsigned short*)(ws + 2 * MB16);
  unsigned short* Og  = (unsigned short*)(ws + 3 * MB16);
  unsigned short* qb  = (unsigned short*)(ws + 4 * MB16);
  unsigned short* kb  = (unsigned short*)(ws + 5 * MB16);
  unsigned short* vb  = (unsigned short*)(ws + 6 * MB16);
  unsigned short* wqb = (unsigned short*)(ws + 7 * MB16);
  unsigned short* wkb = wqb + DD;
  unsigned short* wvb = wkb + DD;
  unsigned short* wob = wvb + DD;

  float* Kout = out + BTD;
  float* Vout = out + 2 * BTD;

  cast_k<<<dim3(4096, 7), 256, 0, stream>>>(q, k, v, wq, wk, wv, wo,
                                            qb, kb, vb, wqb, wkb, wvb, wob);

  gemm_qkv<<<dim3(Ndim / 256, Mdim / 256, 3), 512, 0, stream>>>(
      qb, kb, vb, wqb, wkb, wvb, Qh, Kh, Kout, VTg, Vout);

  attn_k<<<dim3(4 * NH, 16), 256, 0, stream>>>(Qh, Kh, VTg, Og);

  gemm_o<<<dim3(Ndim / 128, Mdim / 128), 256, 0, stream>>>(Og, wob, out);
}

// Round 3
// 366.535 us; speedup vs baseline: 1.0501x; 1.0004x over previous
//
#include <hip/hip_runtime.h>
#include <hip/hip_bf16.h>
#include <math.h>

// Problem constants: B=4, T=2048, D=1024, H=16, DH=64
constexpr int Mdim = 8192;   // B*T
constexpr int Ndim = 1024;
constexpr int Kdim = 1024;
constexpr int Tseq = 2048;
constexpr int NH   = 16;

typedef __attribute__((ext_vector_type(8))) short short8;   // 8 bf16 = 4 VGPRs
typedef __attribute__((ext_vector_type(4))) float floatx4;  // MFMA C/D frag

__device__ __forceinline__ unsigned short f2b(float f) {   // RNE
  unsigned int x = __builtin_bit_cast(unsigned int, f);
  x += 0x7fffu + ((x >> 16) & 1u);
  return (unsigned short)(x >> 16);
}
__device__ __forceinline__ unsigned int pk2(float a, float b) {  // fast 2xbf16
  unsigned int ua = __builtin_bit_cast(unsigned int, a) + 0x8000u;
  unsigned int ub = __builtin_bit_cast(unsigned int, b) + 0x8000u;
  return (ua >> 16) | (ub & 0xffff0000u);
}
// async global->LDS, 16B per lane; LDS dest = uniform base + lane*16
__device__ __forceinline__ void gld16(const void* g, const void* l) {
  __builtin_amdgcn_global_load_lds(
      (const __attribute__((address_space(1))) unsigned int*)(unsigned long long)g,
      (__attribute__((address_space(3))) unsigned int*)(unsigned int)(unsigned long long)l,
      16, 0, 0);
}
// Raw barrier with NO memory-clobber fences: a "memory" asm makes hipcc
// conservatively drain vmcnt/lgkmcnt (== __syncthreads semantics), which
// defeats the counted-vmcnt pipeline (T4). sched_barrier(0) pins program
// order across the barrier without any waitcnt semantics (rule #18 tool).
__device__ __forceinline__ void barrier_raw() {
  __builtin_amdgcn_sched_barrier(0);
  __builtin_amdgcn_s_barrier();
  __builtin_amdgcn_sched_barrier(0);
}

// ---------------------------------------------------------------- casts
__global__ __launch_bounds__(256) void cast_k(
    const float* __restrict__ q, const float* __restrict__ k,
    const float* __restrict__ v, const float* __restrict__ wq,
    const float* __restrict__ wk, const float* __restrict__ wv,
    const float* __restrict__ wo,
    unsigned short* d0, unsigned short* d1, unsigned short* d2,
    unsigned short* d3, unsigned short* d4, unsigned short* d5,
    unsigned short* d6) {
  int y = blockIdx.y;
  const float* s = y == 0 ? q : y == 1 ? k : y == 2 ? v
                 : y == 3 ? wq : y == 4 ? wk : y == 5 ? wv : wo;
  unsigned short* d = y == 0 ? d0 : y == 1 ? d1 : y == 2 ? d2
                    : y == 3 ? d3 : y == 4 ? d4 : y == 5 ? d5 : d6;
  size_t n = (y < 3) ? (size_t)Mdim * Kdim : (size_t)Ndim * Kdim;
  size_t i = ((size_t)blockIdx.x * 256 + threadIdx.x) * 8;
  if (i >= n) return;
  float4 a = *(const float4*)(s + i);
  float4 b = *(const float4*)(s + i + 4);
  uint4 w;
  w.x = (unsigned)f2b(a.x) | ((unsigned)f2b(a.y) << 16);
  w.y = (unsigned)f2b(a.z) | ((unsigned)f2b(a.w) << 16);
  w.z = (unsigned)f2b(b.x) | ((unsigned)f2b(b.y) << 16);
  w.w = (unsigned)f2b(b.z) | ((unsigned)f2b(b.w) << 16);
  *(uint4*)(d + i) = w;
}

// ---------------------------------------------------------------- QKV GEMM
// 256x256 tile, BK=64, 8 waves (2M x 4N), 512 threads — 8-phase schedule
// (T3+T4 counted vmcnt + T5 setprio on top of T2 XOR swizzle).
// ROUND 3: drain-free barriers (sched_barrier-pinned raw s_barrier, no
// "memory" asm clobbers anywhere in the loop) so the counted vmcnt(8)
// actually keeps tile t+2's loads in flight across barriers.
// MFMA operands SWAPPED (A-op = W rows) -> C^T frag: 4 consecutive n per
// lane -> packed float4/ushort4 epilogue stores.
// z: 0 = Q -> Qh bf16 split-head; 1 = K -> Kout f32 + Kh bf16;
//    2 = V -> Vout f32 + VTg bf16 [B,H,64,T].
__launch_bounds__(512, 2)
__global__ void gemm_qkv(const unsigned short* __restrict__ Aq,
                         const unsigned short* __restrict__ Ak,
                         const unsigned short* __restrict__ Av,
                         const unsigned short* __restrict__ Wq,
                         const unsigned short* __restrict__ Wk,
                         const unsigned short* __restrict__ Wv,
                         unsigned short* __restrict__ Qh,
                         unsigned short* __restrict__ Kh,
                         float* __restrict__ Kout,
                         unsigned short* __restrict__ VTg,
                         float* __restrict__ Vout) {
  __shared__ __align__(16) unsigned short As[2][2][8192];  // [par][half][128*64]
  __shared__ __align__(16) unsigned short Bs[2][2][8192];

  const int z = blockIdx.z;
  const unsigned short* __restrict__ A = z == 0 ? Aq : z == 1 ? Ak : Av;
  const unsigned short* __restrict__ W = z == 0 ? Wq : z == 1 ? Wk : Wv;

  const int tid  = threadIdx.x;
  const int lane = tid & 63;
  const int wave = tid >> 6;        // 0..7
  const int mw   = wave >> 2;       // 0..1  (M half of the tile)
  const int nw   = wave & 3;        // 0..3  (64-col N slice)
  const int l15  = lane & 15;
  const int quad = lane >> 4;
  const int sw   = l15 & 7;

  // bijective XCD-chunked swizzle: nwg=128 per z-plane, 128%8==0.
  const int flat = blockIdx.y * 4 + blockIdx.x;      // gridDim.x == 4
  const int swz  = (flat & 7) * 16 + (flat >> 3);
  const int m0   = (swz >> 2) * 256;
  const int n0   = (swz & 3) * 256;

  const int srow8 = lane >> 3;
  const int sg    = lane & 7;

  floatx4 acc[2][2][4][2];   // [mh][nh][mi][ni]
#pragma unroll
  for (int a0 = 0; a0 < 2; a0++)
#pragma unroll
    for (int b0 = 0; b0 < 2; b0++)
#pragma unroll
      for (int c0 = 0; c0 < 4; c0++)
#pragma unroll
        for (int d0 = 0; d0 < 2; d0++) acc[a0][b0][c0][d0] = (floatx4)0.0f;

  auto stage = [&](const unsigned short* __restrict__ S, int rb, int kt,
                   unsigned short* dst) {
#pragma unroll
    for (int h = 0; h < 2; h++)
#pragma unroll
      for (int j = 0; j < 2; j++) {
        int c = wave * 2 + j;            // 1KB chunk = 8 rows of 64
        int r = c * 8 + srow8;           // row within half, 0..127
        int G = sg ^ (r & 7);            // pre-swizzled global source
        gld16(S + (size_t)(rb + h * 128 + r) * Kdim + kt + G * 8,
              dst + h * 8192 + c * 512);
      }
  };
  auto ldA = [&](int par, int mh, short8 (&a)[4][2]) {
    const unsigned short* base = &As[par][mw][0];
#pragma unroll
    for (int mi = 0; mi < 4; mi++) {
      const unsigned short* rp = base + (mh * 64 + mi * 16 + l15) * 64;
#pragma unroll
      for (int ks = 0; ks < 2; ks++)
        a[mi][ks] = *(const short8*)(rp + (((ks * 4 + quad) ^ sw) << 3));
    }
  };
  auto ldB = [&](int par, int nh, short8 (&b)[2][2]) {
    const unsigned short* base = &Bs[par][nw >> 1][0];
#pragma unroll
    for (int ni = 0; ni < 2; ni++) {
      const unsigned short* rp =
          base + ((nw & 1) * 64 + nh * 32 + ni * 16 + l15) * 64;
#pragma unroll
      for (int ks = 0; ks < 2; ks++)
        b[ni][ks] = *(const short8*)(rp + (((ks * 4 + quad) ^ sw) << 3));
    }
  };
  auto mmaq = [&](floatx4 (&c)[4][2], short8 (&a)[4][2], short8 (&b)[2][2]) {
    __builtin_amdgcn_s_setprio(1);
#pragma unroll
    for (int mi = 0; mi < 4; mi++)
#pragma unroll
      for (int ni = 0; ni < 2; ni++)
#pragma unroll
        for (int ks = 0; ks < 2; ks++)
          c[mi][ni] = __builtin_amdgcn_mfma_f32_16x16x32_bf16(
              b[ni][ks], a[mi][ks], c[mi][ni], 0, 0, 0);   // swapped: C^T
    __builtin_amdgcn_s_setprio(0);
  };

  // prologue: tiles 0 (parity 0) and 1 (parity 1); wait tile 0 resident.
  stage(A, m0, 0, &As[0][0][0]);
  stage(W, n0, 0, &Bs[0][0][0]);
  stage(A, m0, 64, &As[1][0][0]);
  stage(W, n0, 64, &Bs[1][0][0]);
  __builtin_amdgcn_sched_barrier(0);
  asm volatile("s_waitcnt vmcnt(8)");
  barrier_raw();

  short8 a[4][2], b0[2][2], b1[2][2];
  constexpr int NT = Kdim / 64;   // 16
  for (int t = 0; t < NT; ++t) {
    const int par = t & 1;
    const int ktn = (t + 2) * 64;
    // ---- phase 1: read A(m0)[8] + B(n0)[4]; MFMA quad (0,0)
    ldA(par, 0, a);
    ldB(par, 0, b0);
    barrier_raw();
    mmaq(acc[0][0], a, b0);
    barrier_raw();
    // ---- phase 2: read B(n1)[4]; MFMA quad (0,1)
    ldB(par, 1, b1);
    barrier_raw();
    mmaq(acc[0][1], a, b1);
    barrier_raw();
    // ---- phase 3: read A(m1)[8]; issue B(t+2) (B slots freed at ph2 bar)
    ldA(par, 1, a);
    if (t < NT - 2) stage(W, n0, ktn, &Bs[par][0][0]);
    barrier_raw();
    mmaq(acc[1][0], a, b0);
    barrier_raw();
    // ---- phase 4: issue A(t+2) (A slots freed at ph3 bar); MFMA quad (1,1)
    if (t < NT - 2) stage(A, m0, ktn, &As[par][0][0]);
    barrier_raw();
    mmaq(acc[1][1], a, b1);
    // tile boundary: counted vmcnt — newest 8 loads = tile t+2's; everything
    // older (incl. tile t+1) is resident. Drain fully only entering last tile.
    __builtin_amdgcn_sched_barrier(0);
    if (t < NT - 2)
      asm volatile("s_waitcnt vmcnt(8)");
    else if (t == NT - 2)
      asm volatile("s_waitcnt vmcnt(0)");
    barrier_raw();
  }

  // Epilogue. C^T: frag rows (quad*4+r) = n (dh), frag col (l15) = m (t).
  const int gmb = m0 + mw * 128;
  const int gnb = n0 + nw * 64;
#pragma unroll
  for (int mh = 0; mh < 2; mh++)
#pragma unroll
    for (int mi = 0; mi < 4; mi++) {
      int t_abs = gmb + mh * 64 + mi * 16 + l15;
      int b = t_abs >> 11, tb = t_abs & (Tseq - 1);
#pragma unroll
      for (int nh = 0; nh < 2; nh++)
#pragma unroll
        for (int ni = 0; ni < 2; ni++) {
          int gn0 = gnb + nh * 32 + ni * 16 + quad * 4;
          int h = gn0 >> 6, dh0 = gn0 & 63;
          size_t base = ((size_t)((b * NH + h) * Tseq + tb)) * 64 + dh0;
          floatx4 v = acc[mh][nh][mi][ni];
          if (z == 0) {
            ushort4 w = {f2b(v[0]), f2b(v[1]), f2b(v[2]), f2b(v[3])};
            *(ushort4*)(Qh + base) = w;
          } else if (z == 1) {
            *(float4*)(Kout + base) = *(float4*)&v;
            ushort4 w = {f2b(v[0]), f2b(v[1]), f2b(v[2]), f2b(v[3])};
            *(ushort4*)(Kh + base) = w;
          } else {
            *(float4*)(Vout + base) = *(float4*)&v;
            size_t vtb = ((size_t)((b * NH + h) * 64 + dh0)) * Tseq + tb;
#pragma unroll
            for (int r = 0; r < 4; r++)
              VTg[vtb + (size_t)r * Tseq] = f2b(v[r]);   // 16-lane 32B segments
          }
        }
    }
}

// ---------------------------------------------------------------- O GEMM
// out[M,N] f32 = Og[M,K] bf16 * Wo[N,K]^T bf16.  128² 2-phase structure.
// Uses __syncthreads (full drain) — correctness of gld16->read ordering
// here relies on it; untouched this round.
__launch_bounds__(256)
__global__ void gemm_o(const unsigned short* __restrict__ A,
                       const unsigned short* __restrict__ W,
                       float* __restrict__ Cf) {
  __shared__ __align__(16) unsigned short As[128 * 64];
  __shared__ __align__(16) unsigned short Bs[128 * 64];

  const int tid  = threadIdx.x;
  const int lane = tid & 63;
  const int wave = tid >> 6;
  const int l15  = lane & 15;
  const int quad = lane >> 4;
  const int sw   = l15 & 7;
  const int m0 = blockIdx.y * 128;
  const int n0 = blockIdx.x * 128;
  const int wm = (wave >> 1) * 64;
  const int wn = (wave & 1) * 64;

  floatx4 acc[4][4];
  for (int i = 0; i < 4; i++)
    for (int j = 0; j < 4; j++) acc[i][j] = (floatx4)0.0f;

  const int srow8 = lane >> 3;
  const int sg    = lane & 7;

  for (int kt = 0; kt < Kdim; kt += 64) {
    for (int jj = 0; jj < 4; jj++) {
      int cc = wave * 4 + jj;
      int row = cc * 8 + srow8;
      int G = sg ^ (row & 7);
      gld16(A + (size_t)(m0 + row) * Kdim + kt + G * 8, As + cc * 512);
      gld16(W + (size_t)(n0 + row) * Kdim + kt + G * 8, Bs + cc * 512);
    }
    __syncthreads();

    for (int hf = 0; hf < 2; hf++) {
      short8 af[4], bw[4];
      for (int mi = 0; mi < 4; mi++)
        af[mi] = *(const short8*)(As + (wm + mi * 16 + l15) * 64 +
                                  (((hf * 4 + quad) ^ sw) << 3));
      for (int ni = 0; ni < 4; ni++)
        bw[ni] = *(const short8*)(Bs + (wn + ni * 16 + l15) * 64 +
                                  (((hf * 4 + quad) ^ sw) << 3));
      for (int mi = 0; mi < 4; mi++)
        for (int ni = 0; ni < 4; ni++)
          acc[mi][ni] = __builtin_amdgcn_mfma_f32_16x16x32_bf16(
              bw[ni], af[mi], acc[mi][ni], 0, 0, 0);
    }
    __syncthreads();
  }

  for (int mi = 0; mi < 4; mi++) {
    int t_abs = m0 + wm + mi * 16 + l15;
    for (int ni = 0; ni < 4; ni++) {
      int gn0 = n0 + wn + ni * 16 + quad * 4;
      floatx4 v = acc[mi][ni];
      *(float4*)(Cf + (size_t)t_abs * Ndim + gn0) = *(float4*)&v;
    }
  }
}

// ---------------------------------------------------------------- attention
// Causal flash attention, S^T formulation. QBLK=64 (4 waves x 16 q-rows),
// KVBLK=64 double-buffered; block handles q-tile pair (31-p, p) = exactly
// 33 kv-iters -> perfect balance. 40KB LDS -> 4 blocks/CU. Per iter: issue
// next K/V stage first, compute tile t, then vmcnt(0)+raw barrier (drain-
// free barriers; the vmcnt(0) here is the intended wait on own prefetch).
// Defer-max (T13, THR=8 log2-units).
__launch_bounds__(256)
__global__ void attn_k(const unsigned short* __restrict__ Qh,
                       const unsigned short* __restrict__ Kh,
                       const unsigned short* __restrict__ VTg,
                       unsigned short* __restrict__ Og) {
  __shared__ __align__(16) unsigned short Kt[2][64 * 64];
  __shared__ __align__(16) unsigned short Vt[2][64 * 64];
  __shared__ __align__(16) unsigned short Pl[64 * 64];

  const int tid  = threadIdx.x;
  const int lane = tid & 63;
  const int wave = tid >> 6;
  const int l15  = lane & 15;
  const int quad = lane >> 4;
  const int sw   = l15 & 7;
  const int bh   = blockIdx.x;

  const size_t headoff = (size_t)bh * Tseq * 64;
  const int srow8 = lane >> 3;
  const int sg    = lane & 7;
  const float kscale = 0.18033688011112042f;  // (1/8) * log2(e)
  const int b = bh >> 4, h = bh & 15;

  for (int half = 0; half < 2; half++) {
    const int a   = half ? blockIdx.y : 31 - blockIdx.y;  // 64-row q-tile idx
    const int nkt = a + 1;
    const int qg  = a * 64 + wave * 16 + l15;   // this lane's q row

    short8 bq[2];
#pragma unroll
    for (int hf = 0; hf < 2; hf++)
      bq[hf] = *(const short8*)(Qh + headoff + (size_t)qg * 64 +
                                hf * 32 + quad * 8);

    floatx4 o[4];
#pragma unroll
    for (int nb = 0; nb < 4; nb++) o[nb] = (floatx4)0.0f;
    float mrow = -INFINITY, lrow = 0.0f;

    auto stage = [&](int par, int kt) {
      const int k0 = kt * 64;
#pragma unroll
      for (int jj = 0; jj < 2; jj++) {
        int cc  = wave * 2 + jj;
        int row = cc * 8 + srow8;
        int G   = sg ^ (row & 7);
        gld16(Kh + headoff + (size_t)(k0 + row) * 64 + G * 8,
              &Kt[par][cc * 512]);
        gld16(VTg + ((size_t)bh * 64 + row) * Tseq + k0 + G * 8,
              &Vt[par][cc * 512]);
      }
    };

    stage(0, 0);
    __builtin_amdgcn_sched_barrier(0);
    asm volatile("s_waitcnt vmcnt(0)");
    barrier_raw();

    for (int kt = 0; kt < nkt; kt++) {
      const int par = kt & 1;
      if (kt + 1 < nkt) stage(par ^ 1, kt + 1);   // prefetch hides under compute
      const int k0 = kt * 64;

      // QK^T (S^T frag: lane l15 = q-row, quad*4+r (+16nb) = k)
      floatx4 st[4];
#pragma unroll
      for (int nb = 0; nb < 4; nb++) {
        const unsigned short* kr = &Kt[par][(nb * 16 + l15) * 64];
        short8 ak0 = *(const short8*)(kr + ((quad ^ sw) << 3));
        short8 ak1 = *(const short8*)(kr + (((quad + 4) ^ sw) << 3));
        floatx4 acc0 = (floatx4)0.0f;
        acc0 = __builtin_amdgcn_mfma_f32_16x16x32_bf16(ak0, bq[0], acc0, 0, 0, 0);
        acc0 = __builtin_amdgcn_mfma_f32_16x16x32_bf16(ak1, bq[1], acc0, 0, 0, 0);
        st[nb] = acc0;
      }

      if (kt == nkt - 1) {   // only the diagonal tile needs masking
#pragma unroll
        for (int nb = 0; nb < 4; nb++)
#pragma unroll
          for (int r = 0; r < 4; r++) {
            int kg = k0 + nb * 16 + quad * 4 + r;
            if (kg > qg) st[nb][r] = -INFINITY;
          }
      }

      // row max (wave-parallel: quad lanes hold the row's 4 k-chunks)
      float mt = fmaxf(fmaxf(st[0][0], st[0][1]), fmaxf(st[0][2], st[0][3]));
#pragma unroll
      for (int nb = 1; nb < 4; nb++)
        mt = fmaxf(mt, fmaxf(fmaxf(st[nb][0], st[nb][1]),
                             fmaxf(st[nb][2], st[nb][3])));
      mt = fmaxf(mt, __shfl_xor(mt, 16, 64));
      mt = fmaxf(mt, __shfl_xor(mt, 32, 64));

      // T13 defer-max: skip rescale while growth <= 8 log2-units (P <= 2^8)
      if (!__all((mt - mrow) * kscale <= 8.0f)) {
        float mnew = fmaxf(mrow, mt);
        float al = __builtin_amdgcn_exp2f((mrow - mnew) * kscale);
        mrow = mnew;
        lrow *= al;
#pragma unroll
        for (int nb = 0; nb < 4; nb++)
#pragma unroll
          for (int r = 0; r < 4; r++) o[nb][r] *= al;
      }
      const float ms = mrow * kscale;

      float rs = 0.0f;
      const int prow = (wave * 16 + l15) * 64;
#pragma unroll
      for (int nb = 0; nb < 4; nb++) {
        float p0 = __builtin_amdgcn_exp2f(__builtin_fmaf(st[nb][0], kscale, -ms));
        float p1 = __builtin_amdgcn_exp2f(__builtin_fmaf(st[nb][1], kscale, -ms));
        float p2 = __builtin_amdgcn_exp2f(__builtin_fmaf(st[nb][2], kscale, -ms));
        float p3 = __builtin_amdgcn_exp2f(__builtin_fmaf(st[nb][3], kscale, -ms));
        rs += (p0 + p1) + (p2 + p3);
        uint2 w = {pk2(p0, p1), pk2(p2, p3)};
        int klb = nb * 16 + quad * 4;
        int colp = (((klb >> 3) ^ sw) << 3) | (klb & 7);
        *(uint2*)(Pl + prow + colp) = w;
      }
      rs += __shfl_xor(rs, 16, 64);
      rs += __shfl_xor(rs, 32, 64);
      lrow += rs;

      // PV
      short8 av[4][2];
#pragma unroll
      for (int nb = 0; nb < 4; nb++) {
        const unsigned short* vr = &Vt[par][(nb * 16 + l15) * 64];
        av[nb][0] = *(const short8*)(vr + ((quad ^ sw) << 3));
        av[nb][1] = *(const short8*)(vr + (((quad + 4) ^ sw) << 3));
      }
      const unsigned short* pr = Pl + prow;
      short8 bp0 = *(const short8*)(pr + ((quad ^ sw) << 3));
      short8 bp1 = *(const short8*)(pr + (((quad + 4) ^ sw) << 3));
#pragma unroll
      for (int nb = 0; nb < 4; nb++) {
        o[nb] = __builtin_amdgcn_mfma_f32_16x16x32_bf16(av[nb][0], bp0, o[nb], 0, 0, 0);
        o[nb] = __builtin_amdgcn_mfma_f32_16x16x32_bf16(av[nb][1], bp1, o[nb], 0, 0, 0);
      }

      // wait own prefetch; barrier publishes all waves' stages for next iter
      __builtin_amdgcn_sched_barrier(0);
      asm volatile("s_waitcnt vmcnt(0)");
      barrier_raw();
    }

    float inv = 1.0f / lrow;
    size_t rowoff = ((size_t)(b * Tseq + qg)) * 1024 + h * 64;
#pragma unroll
    for (int nb = 0; nb < 4; nb++) {
      ushort4 w;
      w.x = f2b(o[nb][0] * inv);
      w.y = f2b(o[nb][1] * inv);
      w.z = f2b(o[nb][2] * inv);
      w.w = f2b(o[nb][3] * inv);
      *(ushort4*)(Og + rowoff + nb * 16 + quad * 4) = w;
    }
  }
}

// ---------------------------------------------------------------- launcher
extern "C" void kernel_launch(void* const* d_in, const int* in_sizes, int n_in,
                              void* d_out, int out_size, void* d_ws, size_t ws_size,
                              hipStream_t stream) {
  const float* q  = (const float*)d_in[0];
  const float* k  = (const float*)d_in[1];
  const float* v  = (const float*)d_in[2];
  const float* wq = (const float*)d_in[3];
  const float* wk = (const float*)d_in[4];
  const float* wv = (const float*)d_in[5];
  const float* wo = (const float*)d_in[6];
  // d_in[7] = attn_mask: deterministically causal; handled analytically.
  float* out = (float*)d_out;

  constexpr size_t BTD = (size_t)Mdim * Kdim;
  constexpr size_t DD  = (size_t)Ndim * Kdim;
  constexpr size_t MB16 = BTD * 2;

  char* ws = (char*)d_ws;
  unsigned short* Qh  = (unsigned short*)(ws);
  unsigned short* Kh  = (unsigned short*)(ws + MB16);
  unsigned short* VTg = (unsigned short*)(ws + 2 * MB16);
  unsigned short* Og  = (unsigned short*)(ws + 3 * MB16);
  unsigned short* qb  = (unsigned short*)(ws + 4 * MB16);
  unsigned short* kb  = (unsigned short*)(ws + 5 * MB16);
  unsigned short* vb  = (unsigned short*)(ws + 6 * MB16);
  unsigned short* wqb = (unsigned short*)(ws + 7 * MB16);
  unsigned short* wkb = wqb + DD;
  unsigned short* wvb = wkb + DD;
  unsigned short* wob = wvb + DD;

  float* Kout = out + BTD;
  float* Vout = out + 2 * BTD;

  cast_k<<<dim3(4096, 7), 256, 0, stream>>>(q, k, v, wq, wk, wv, wo,
                                            qb, kb, vb, wqb, wkb, wvb, wob);

  gemm_qkv<<<dim3(Ndim / 256, Mdim / 256, 3), 512, 0, stream>>>(
      qb, kb, vb, wqb, wkb, wvb, Qh, Kh, Kout, VTg, Vout);

  attn_k<<<dim3(4 * NH, 16), 256, 0, stream>>>(Qh, Kh, VTg, Og);

  gemm_o<<<dim3(Ndim / 128, Mdim / 128), 256, 0, stream>>>(Og, wob, out);
}

// Round 4
// 366.221 us; speedup vs baseline: 1.0510x; 1.0009x over previous
//
#include <hip/hip_runtime.h>
#include <hip/hip_bf16.h>
#include <math.h>

// Problem constants: B=4, T=2048, D=1024, H=16, DH=64
constexpr int Mdim = 8192;   // B*T
constexpr int Ndim = 1024;
constexpr int Kdim = 1024;
constexpr int Tseq = 2048;
constexpr int NH   = 16;

typedef __attribute__((ext_vector_type(8))) short short8;   // 8 bf16 = 4 VGPRs
typedef __attribute__((ext_vector_type(4))) float floatx4;  // MFMA C/D frag

__device__ __forceinline__ unsigned short f2b(float f) {   // RNE
  unsigned int x = __builtin_bit_cast(unsigned int, f);
  x += 0x7fffu + ((x >> 16) & 1u);
  return (unsigned short)(x >> 16);
}
__device__ __forceinline__ unsigned int pk2(float a, float b) {  // fast 2xbf16
  unsigned int ua = __builtin_bit_cast(unsigned int, a) + 0x8000u;
  unsigned int ub = __builtin_bit_cast(unsigned int, b) + 0x8000u;
  return (ua >> 16) | (ub & 0xffff0000u);
}
// async global->LDS, 16B per lane; LDS dest = uniform base + lane*16
__device__ __forceinline__ void gld16(const void* g, const void* l) {
  __builtin_amdgcn_global_load_lds(
      (const __attribute__((address_space(1))) unsigned int*)(unsigned long long)g,
      (__attribute__((address_space(3))) unsigned int*)(unsigned int)(unsigned long long)l,
      16, 0, 0);
}
// Raw barrier without waitcnt drain (sched_barrier pins program order only).
__device__ __forceinline__ void barrier_raw() {
  __builtin_amdgcn_sched_barrier(0);
  __builtin_amdgcn_s_barrier();
  __builtin_amdgcn_sched_barrier(0);
}

// ---------------------------------------------------------------- casts
__global__ __launch_bounds__(256) void cast_k(
    const float* __restrict__ q, const float* __restrict__ k,
    const float* __restrict__ v, const float* __restrict__ wq,
    const float* __restrict__ wk, const float* __restrict__ wv,
    const float* __restrict__ wo,
    unsigned short* d0, unsigned short* d1, unsigned short* d2,
    unsigned short* d3, unsigned short* d4, unsigned short* d5,
    unsigned short* d6) {
  int y = blockIdx.y;
  const float* s = y == 0 ? q : y == 1 ? k : y == 2 ? v
                 : y == 3 ? wq : y == 4 ? wk : y == 5 ? wv : wo;
  unsigned short* d = y == 0 ? d0 : y == 1 ? d1 : y == 2 ? d2
                    : y == 3 ? d3 : y == 4 ? d4 : y == 5 ? d5 : d6;
  size_t n = (y < 3) ? (size_t)Mdim * Kdim : (size_t)Ndim * Kdim;
  size_t i = ((size_t)blockIdx.x * 256 + threadIdx.x) * 8;
  if (i >= n) return;
  float4 a = *(const float4*)(s + i);
  float4 b = *(const float4*)(s + i + 4);
  uint4 w;
  w.x = (unsigned)f2b(a.x) | ((unsigned)f2b(a.y) << 16);
  w.y = (unsigned)f2b(a.z) | ((unsigned)f2b(a.w) << 16);
  w.z = (unsigned)f2b(b.x) | ((unsigned)f2b(b.y) << 16);
  w.w = (unsigned)f2b(b.z) | ((unsigned)f2b(b.w) << 16);
  *(uint4*)(d + i) = w;
}

// ---------------------------------------------------------------- QKV GEMM
// ROUND 4: revert to the proven 128x128 / BK=64 / 4-wave 2-phase structure
// (m97-family: multi-block wave overlap hides the barrier drain — m114),
// plus the two levers round-0 lacked:
//   (a) bijective XCD-chunked block swizzle over the FULL 1536-block grid
//       (z folded in; chunk=192 -> each XCD streams one z-plane's m-panels
//       with n innermost: A-panel fetched once then 7x L2 hits, W resident)
//   (b) __launch_bounds__(256,4) -> 4 blocks/CU guaranteed (32KB LDS each).
// MFMA operands SWAPPED (A-op = W rows) -> C^T frag: 4 consecutive n per
// lane -> packed float4/ushort4 epilogue stores.
// z: 0 = Q -> Qh bf16 split-head; 1 = K -> Kout f32 + Kh bf16;
//    2 = V -> Vout f32 + VTg bf16 [B,H,64,T].
__launch_bounds__(256, 4)
__global__ void gemm_qkv(const unsigned short* __restrict__ Aq,
                         const unsigned short* __restrict__ Ak,
                         const unsigned short* __restrict__ Av,
                         const unsigned short* __restrict__ Wq,
                         const unsigned short* __restrict__ Wk,
                         const unsigned short* __restrict__ Wv,
                         unsigned short* __restrict__ Qh,
                         unsigned short* __restrict__ Kh,
                         float* __restrict__ Kout,
                         unsigned short* __restrict__ VTg,
                         float* __restrict__ Vout) {
  __shared__ __align__(16) unsigned short As[128 * 64];
  __shared__ __align__(16) unsigned short Bs[128 * 64];

  // bijective XCD-chunked swizzle: nwg = 8*64*3 = 1536, 1536%8==0, chunk 192.
  const int flat = (blockIdx.z * 64 + blockIdx.y) * 8 + blockIdx.x;
  const int wgid = (flat & 7) * 192 + (flat >> 3);
  const int z    = wgid >> 9;            // 512 tiles per z-plane
  const int rem  = wgid & 511;
  const int m0   = (rem >> 3) * 128;     // 64 m-tiles
  const int n0   = (rem & 7) * 128;      // 8 n-tiles (innermost: A-panel reuse)

  const unsigned short* __restrict__ A = z == 0 ? Aq : z == 1 ? Ak : Av;
  const unsigned short* __restrict__ W = z == 0 ? Wq : z == 1 ? Wk : Wv;

  const int tid  = threadIdx.x;
  const int lane = tid & 63;
  const int wave = tid >> 6;
  const int l15  = lane & 15;
  const int quad = lane >> 4;
  const int sw   = l15 & 7;
  const int wm = (wave >> 1) * 64;
  const int wn = (wave & 1) * 64;

  floatx4 acc[4][4];
  for (int i = 0; i < 4; i++)
    for (int j = 0; j < 4; j++) acc[i][j] = (floatx4)0.0f;

  const int srow8 = lane >> 3;   // staging: 8 lanes per 64-col row
  const int sg    = lane & 7;

  for (int kt = 0; kt < Kdim; kt += 64) {
    for (int jj = 0; jj < 4; jj++) {
      int cc = wave * 4 + jj;            // 1KB chunk = 8 rows
      int row = cc * 8 + srow8;
      int G = sg ^ (row & 7);
      gld16(A + (size_t)(m0 + row) * Kdim + kt + G * 8, As + cc * 512);
      gld16(W + (size_t)(n0 + row) * Kdim + kt + G * 8, Bs + cc * 512);
    }
    __syncthreads();

    for (int hf = 0; hf < 2; hf++) {
      short8 af[4], bw[4];
      for (int mi = 0; mi < 4; mi++)
        af[mi] = *(const short8*)(As + (wm + mi * 16 + l15) * 64 +
                                  (((hf * 4 + quad) ^ sw) << 3));
      for (int ni = 0; ni < 4; ni++)
        bw[ni] = *(const short8*)(Bs + (wn + ni * 16 + l15) * 64 +
                                  (((hf * 4 + quad) ^ sw) << 3));
      for (int mi = 0; mi < 4; mi++)
        for (int ni = 0; ni < 4; ni++)
          acc[mi][ni] = __builtin_amdgcn_mfma_f32_16x16x32_bf16(
              bw[ni], af[mi], acc[mi][ni], 0, 0, 0);   // swapped: C^T
    }
    __syncthreads();
  }

  // Epilogue. C^T: lane row (quad*4+r) = n (dh), lane col (l15) = m (t).
  const int gm = m0 + wm + l15;              // t-row base for mi=0 (+16 per mi)
  for (int mi = 0; mi < 4; mi++) {
    int t_abs = gm + mi * 16;
    int b = t_abs >> 11, tb = t_abs & (Tseq - 1);
    for (int ni = 0; ni < 4; ni++) {
      int gn0 = n0 + wn + ni * 16 + quad * 4;
      int h = gn0 >> 6, dh0 = gn0 & 63;
      size_t base = ((size_t)((b * NH + h) * Tseq + tb)) * 64 + dh0;
      floatx4 v = acc[mi][ni];
      if (z == 0) {
        ushort4 w = {f2b(v[0]), f2b(v[1]), f2b(v[2]), f2b(v[3])};
        *(ushort4*)(Qh + base) = w;
      } else if (z == 1) {
        *(float4*)(Kout + base) = *(float4*)&v;
        ushort4 w = {f2b(v[0]), f2b(v[1]), f2b(v[2]), f2b(v[3])};
        *(ushort4*)(Kh + base) = w;
      } else {
        *(float4*)(Vout + base) = *(float4*)&v;
        size_t vtb = ((size_t)((b * NH + h) * 64 + dh0)) * Tseq + tb;
        for (int r = 0; r < 4; r++)
          VTg[vtb + (size_t)r * Tseq] = f2b(v[r]);   // 16-lane 32B segments
      }
    }
  }
}

// ---------------------------------------------------------------- O GEMM
// out[M,N] f32 = Og[M,K] bf16 * Wo[N,K]^T bf16.  128² 2-phase structure
// (unchanged this round — attribution stays on gemm_qkv).
__launch_bounds__(256)
__global__ void gemm_o(const unsigned short* __restrict__ A,
                       const unsigned short* __restrict__ W,
                       float* __restrict__ Cf) {
  __shared__ __align__(16) unsigned short As[128 * 64];
  __shared__ __align__(16) unsigned short Bs[128 * 64];

  const int tid  = threadIdx.x;
  const int lane = tid & 63;
  const int wave = tid >> 6;
  const int l15  = lane & 15;
  const int quad = lane >> 4;
  const int sw   = l15 & 7;
  const int m0 = blockIdx.y * 128;
  const int n0 = blockIdx.x * 128;
  const int wm = (wave >> 1) * 64;
  const int wn = (wave & 1) * 64;

  floatx4 acc[4][4];
  for (int i = 0; i < 4; i++)
    for (int j = 0; j < 4; j++) acc[i][j] = (floatx4)0.0f;

  const int srow8 = lane >> 3;
  const int sg    = lane & 7;

  for (int kt = 0; kt < Kdim; kt += 64) {
    for (int jj = 0; jj < 4; jj++) {
      int cc = wave * 4 + jj;
      int row = cc * 8 + srow8;
      int G = sg ^ (row & 7);
      gld16(A + (size_t)(m0 + row) * Kdim + kt + G * 8, As + cc * 512);
      gld16(W + (size_t)(n0 + row) * Kdim + kt + G * 8, Bs + cc * 512);
    }
    __syncthreads();

    for (int hf = 0; hf < 2; hf++) {
      short8 af[4], bw[4];
      for (int mi = 0; mi < 4; mi++)
        af[mi] = *(const short8*)(As + (wm + mi * 16 + l15) * 64 +
                                  (((hf * 4 + quad) ^ sw) << 3));
      for (int ni = 0; ni < 4; ni++)
        bw[ni] = *(const short8*)(Bs + (wn + ni * 16 + l15) * 64 +
                                  (((hf * 4 + quad) ^ sw) << 3));
      for (int mi = 0; mi < 4; mi++)
        for (int ni = 0; ni < 4; ni++)
          acc[mi][ni] = __builtin_amdgcn_mfma_f32_16x16x32_bf16(
              bw[ni], af[mi], acc[mi][ni], 0, 0, 0);
    }
    __syncthreads();
  }

  for (int mi = 0; mi < 4; mi++) {
    int t_abs = m0 + wm + mi * 16 + l15;
    for (int ni = 0; ni < 4; ni++) {
      int gn0 = n0 + wn + ni * 16 + quad * 4;
      floatx4 v = acc[mi][ni];
      *(float4*)(Cf + (size_t)t_abs * Ndim + gn0) = *(float4*)&v;
    }
  }
}

// ---------------------------------------------------------------- attention
// Causal flash attention, S^T formulation. QBLK=64 (4 waves x 16 q-rows),
// KVBLK=64 double-buffered; block handles q-tile pair (31-p, p) = exactly
// 33 kv-iters -> perfect balance. 40KB LDS -> 4 blocks/CU. Per iter: issue
// next K/V stage first, compute tile t, then vmcnt(0)+raw barrier.
// Defer-max (T13, THR=8 log2-units).  (unchanged this round)
__launch_bounds__(256)
__global__ void attn_k(const unsigned short* __restrict__ Qh,
                       const unsigned short* __restrict__ Kh,
                       const unsigned short* __restrict__ VTg,
                       unsigned short* __restrict__ Og) {
  __shared__ __align__(16) unsigned short Kt[2][64 * 64];
  __shared__ __align__(16) unsigned short Vt[2][64 * 64];
  __shared__ __align__(16) unsigned short Pl[64 * 64];

  const int tid  = threadIdx.x;
  const int lane = tid & 63;
  const int wave = tid >> 6;
  const int l15  = lane & 15;
  const int quad = lane >> 4;
  const int sw   = l15 & 7;
  const int bh   = blockIdx.x;

  const size_t headoff = (size_t)bh * Tseq * 64;
  const int srow8 = lane >> 3;
  const int sg    = lane & 7;
  const float kscale = 0.18033688011112042f;  // (1/8) * log2(e)
  const int b = bh >> 4, h = bh & 15;

  for (int half = 0; half < 2; half++) {
    const int a   = half ? blockIdx.y : 31 - blockIdx.y;  // 64-row q-tile idx
    const int nkt = a + 1;
    const int qg  = a * 64 + wave * 16 + l15;   // this lane's q row

    short8 bq[2];
#pragma unroll
    for (int hf = 0; hf < 2; hf++)
      bq[hf] = *(const short8*)(Qh + headoff + (size_t)qg * 64 +
                                hf * 32 + quad * 8);

    floatx4 o[4];
#pragma unroll
    for (int nb = 0; nb < 4; nb++) o[nb] = (floatx4)0.0f;
    float mrow = -INFINITY, lrow = 0.0f;

    auto stage = [&](int par, int kt) {
      const int k0 = kt * 64;
#pragma unroll
      for (int jj = 0; jj < 2; jj++) {
        int cc  = wave * 2 + jj;
        int row = cc * 8 + srow8;
        int G   = sg ^ (row & 7);
        gld16(Kh + headoff + (size_t)(k0 + row) * 64 + G * 8,
              &Kt[par][cc * 512]);
        gld16(VTg + ((size_t)bh * 64 + row) * Tseq + k0 + G * 8,
              &Vt[par][cc * 512]);
      }
    };

    stage(0, 0);
    __builtin_amdgcn_sched_barrier(0);
    asm volatile("s_waitcnt vmcnt(0)");
    barrier_raw();

    for (int kt = 0; kt < nkt; kt++) {
      const int par = kt & 1;
      if (kt + 1 < nkt) stage(par ^ 1, kt + 1);   // prefetch hides under compute
      const int k0 = kt * 64;

      // QK^T (S^T frag: lane l15 = q-row, quad*4+r (+16nb) = k)
      floatx4 st[4];
#pragma unroll
      for (int nb = 0; nb < 4; nb++) {
        const unsigned short* kr = &Kt[par][(nb * 16 + l15) * 64];
        short8 ak0 = *(const short8*)(kr + ((quad ^ sw) << 3));
        short8 ak1 = *(const short8*)(kr + (((quad + 4) ^ sw) << 3));
        floatx4 acc0 = (floatx4)0.0f;
        acc0 = __builtin_amdgcn_mfma_f32_16x16x32_bf16(ak0, bq[0], acc0, 0, 0, 0);
        acc0 = __builtin_amdgcn_mfma_f32_16x16x32_bf16(ak1, bq[1], acc0, 0, 0, 0);
        st[nb] = acc0;
      }

      if (kt == nkt - 1) {   // only the diagonal tile needs masking
#pragma unroll
        for (int nb = 0; nb < 4; nb++)
#pragma unroll
          for (int r = 0; r < 4; r++) {
            int kg = k0 + nb * 16 + quad * 4 + r;
            if (kg > qg) st[nb][r] = -INFINITY;
          }
      }

      // row max (wave-parallel: quad lanes hold the row's 4 k-chunks)
      float mt = fmaxf(fmaxf(st[0][0], st[0][1]), fmaxf(st[0][2], st[0][3]));
#pragma unroll
      for (int nb = 1; nb < 4; nb++)
        mt = fmaxf(mt, fmaxf(fmaxf(st[nb][0], st[nb][1]),
                             fmaxf(st[nb][2], st[nb][3])));
      mt = fmaxf(mt, __shfl_xor(mt, 16, 64));
      mt = fmaxf(mt, __shfl_xor(mt, 32, 64));

      // T13 defer-max: skip rescale while growth <= 8 log2-units (P <= 2^8)
      if (!__all((mt - mrow) * kscale <= 8.0f)) {
        float mnew = fmaxf(mrow, mt);
        float al = __builtin_amdgcn_exp2f((mrow - mnew) * kscale);
        mrow = mnew;
        lrow *= al;
#pragma unroll
        for (int nb = 0; nb < 4; nb++)
#pragma unroll
          for (int r = 0; r < 4; r++) o[nb][r] *= al;
      }
      const float ms = mrow * kscale;

      float rs = 0.0f;
      const int prow = (wave * 16 + l15) * 64;
#pragma unroll
      for (int nb = 0; nb < 4; nb++) {
        float p0 = __builtin_amdgcn_exp2f(__builtin_fmaf(st[nb][0], kscale, -ms));
        float p1 = __builtin_amdgcn_exp2f(__builtin_fmaf(st[nb][1], kscale, -ms));
        float p2 = __builtin_amdgcn_exp2f(__builtin_fmaf(st[nb][2], kscale, -ms));
        float p3 = __builtin_amdgcn_exp2f(__builtin_fmaf(st[nb][3], kscale, -ms));
        rs += (p0 + p1) + (p2 + p3);
        uint2 w = {pk2(p0, p1), pk2(p2, p3)};
        int klb = nb * 16 + quad * 4;
        int colp = (((klb >> 3) ^ sw) << 3) | (klb & 7);
        *(uint2*)(Pl + prow + colp) = w;
      }
      rs += __shfl_xor(rs, 16, 64);
      rs += __shfl_xor(rs, 32, 64);
      lrow += rs;

      // PV
      short8 av[4][2];
#pragma unroll
      for (int nb = 0; nb < 4; nb++) {
        const unsigned short* vr = &Vt[par][(nb * 16 + l15) * 64];
        av[nb][0] = *(const short8*)(vr + ((quad ^ sw) << 3));
        av[nb][1] = *(const short8*)(vr + (((quad + 4) ^ sw) << 3));
      }
      const unsigned short* pr = Pl + prow;
      short8 bp0 = *(const short8*)(pr + ((quad ^ sw) << 3));
      short8 bp1 = *(const short8*)(pr + (((quad + 4) ^ sw) << 3));
#pragma unroll
      for (int nb = 0; nb < 4; nb++) {
        o[nb] = __builtin_amdgcn_mfma_f32_16x16x32_bf16(av[nb][0], bp0, o[nb], 0, 0, 0);
        o[nb] = __builtin_amdgcn_mfma_f32_16x16x32_bf16(av[nb][1], bp1, o[nb], 0, 0, 0);
      }

      // wait own prefetch; barrier publishes all waves' stages for next iter
      __builtin_amdgcn_sched_barrier(0);
      asm volatile("s_waitcnt vmcnt(0)");
      barrier_raw();
    }

    float inv = 1.0f / lrow;
    size_t rowoff = ((size_t)(b * Tseq + qg)) * 1024 + h * 64;
#pragma unroll
    for (int nb = 0; nb < 4; nb++) {
      ushort4 w;
      w.x = f2b(o[nb][0] * inv);
      w.y = f2b(o[nb][1] * inv);
      w.z = f2b(o[nb][2] * inv);
      w.w = f2b(o[nb][3] * inv);
      *(ushort4*)(Og + rowoff + nb * 16 + quad * 4) = w;
    }
  }
}

// ---------------------------------------------------------------- launcher
extern "C" void kernel_launch(void* const* d_in, const int* in_sizes, int n_in,
                              void* d_out, int out_size, void* d_ws, size_t ws_size,
                              hipStream_t stream) {
  const float* q  = (const float*)d_in[0];
  const float* k  = (const float*)d_in[1];
  const float* v  = (const float*)d_in[2];
  const float* wq = (const float*)d_in[3];
  const float* wk = (const float*)d_in[4];
  const float* wv = (const float*)d_in[5];
  const float* wo = (const float*)d_in[6];
  // d_in[7] = attn_mask: deterministically causal; handled analytically.
  float* out = (float*)d_out;

  constexpr size_t BTD = (size_t)Mdim * Kdim;
  constexpr size_t DD  = (size_t)Ndim * Kdim;
  constexpr size_t MB16 = BTD * 2;

  char* ws = (char*)d_ws;
  unsigned short* Qh  = (unsigned short*)(ws);
  unsigned short* Kh  = (unsigned short*)(ws + MB16);
  unsigned short* VTg = (unsigned short*)(ws + 2 * MB16);
  unsigned short* Og  = (unsigned short*)(ws + 3 * MB16);
  unsigned short* qb  = (unsigned short*)(ws + 4 * MB16);
  unsigned short* kb  = (unsigned short*)(ws + 5 * MB16);
  unsigned short* vb  = (unsigned short*)(ws + 6 * MB16);
  unsigned short* wqb = (unsigned short*)(ws + 7 * MB16);
  unsigned short* wkb = wqb + DD;
  unsigned short* wvb = wkb + DD;
  unsigned short* wob = wvb + DD;

  float* Kout = out + BTD;
  float* Vout = out + 2 * BTD;

  cast_k<<<dim3(4096, 7), 256, 0, stream>>>(q, k, v, wq, wk, wv, wo,
                                            qb, kb, vb, wqb, wkb, wvb, wob);

  gemm_qkv<<<dim3(8, 64, 3), 256, 0, stream>>>(
      qb, kb, vb, wqb, wkb, wvb, Qh, Kh, Kout, VTg, Vout);

  attn_k<<<dim3(4 * NH, 16), 256, 0, stream>>>(Qh, Kh, VTg, Og);

  gemm_o<<<dim3(Ndim / 128, Mdim / 128), 256, 0, stream>>>(Og, wob, out);
}